// Round 1
// baseline (965.415 us; speedup 1.0000x reference)
//
#include <hip/hip_runtime.h>
#include <hip/hip_bf16.h>
#include <math.h>

// ---- problem constants ----
#define CB 8
#define CT 6
#define CN 24
#define CL 1024
#define CD 512
#define CH 8
#define CDH 64
#define CTN 144     // T*N
#define CTL 6144    // T*L
#define CMT 96      // CTL/64 m-tiles
#define CEPS 1e-5f

typedef __bf16 bf16x8 __attribute__((ext_vector_type(8)));
typedef float  f32x4  __attribute__((ext_vector_type(4)));

#define MFMA16(a,b,c) __builtin_amdgcn_mfma_f32_16x16x32_bf16(a,b,c,0,0,0)

union BF8 { unsigned short s[8]; bf16x8 v; };

static __device__ __forceinline__ unsigned short f2bf(float x){
    union { float f; unsigned u; } c; c.f = x;
    return (unsigned short)((c.u + 0x7FFFu + ((c.u >> 16) & 1u)) >> 16);
}

static __device__ __forceinline__ bf16x8 cvt8(const float* __restrict__ p){
    const f32x4* q = (const f32x4*)p;
    f32x4 v0 = q[0], v1 = q[1];
    BF8 r;
    r.s[0]=f2bf(v0[0]); r.s[1]=f2bf(v0[1]); r.s[2]=f2bf(v0[2]); r.s[3]=f2bf(v0[3]);
    r.s[4]=f2bf(v1[0]); r.s[5]=f2bf(v1[1]); r.s[6]=f2bf(v1[2]); r.s[7]=f2bf(v1[3]);
    return r.v;
}

static __device__ __forceinline__ bf16x8 ldbf8(const unsigned short* __restrict__ p){
    return *(const bf16x8*)p;
}

// ---- convert the 4 weight matrices to bf16 ----
__global__ void cvt_w_kernel(const float* __restrict__ w0, const float* __restrict__ w1,
                             const float* __restrict__ w2, const float* __restrict__ w3,
                             unsigned short* __restrict__ o0, unsigned short* __restrict__ o1,
                             unsigned short* __restrict__ o2, unsigned short* __restrict__ o3){
    int i = blockIdx.x*blockDim.x + threadIdx.x;
    const int n = CD*CD;
    if      (i < n)   o0[i]       = f2bf(w0[i]);
    else if (i < 2*n) o1[i-n]     = f2bf(w1[i-n]);
    else if (i < 3*n) o2[i-2*n]   = f2bf(w2[i-2*n]);
    else if (i < 4*n) o3[i-3*n]   = f2bf(w3[i-3*n]);
}

// ---- projection GEMM: Y = X @ W^T, head-split output as bf16 ----
// MODE 0: out[((b*H+h)*posPer + pos)*64 + dh]   (qp, kp)
// MODE 1: out[((b*H+h)*64 + dh)*posPer + pos]   (vp transposed)
template<int MODE>
__global__ __launch_bounds__(256) void proj_kernel(
    const float* __restrict__ X, const unsigned short* __restrict__ W,
    unsigned short* __restrict__ out, int posPer, float scale)
{
    __shared__ float tile[64][65];
    int tm = blockIdx.x * 64;
    int ct = blockIdx.y * 64;
    int lane = threadIdx.x & 63, wave = threadIdx.x >> 6;
    int arow = tm + wave*16 + (lane & 15);
    int koff = 8 * (lane >> 4);
    f32x4 acc[4] = {};
    for (int k0 = 0; k0 < CD; k0 += 32) {
        bf16x8 a = cvt8(X + (size_t)arow*CD + k0 + koff);
        #pragma unroll
        for (int cf = 0; cf < 4; ++cf) {
            bf16x8 b = ldbf8(W + (size_t)(ct + cf*16 + (lane&15))*CD + k0 + koff);
            acc[cf] = MFMA16(a, b, acc[cf]);
        }
    }
    int rl = wave*16 + 4*(lane>>4);
    #pragma unroll
    for (int cf = 0; cf < 4; ++cf)
        #pragma unroll
        for (int r = 0; r < 4; ++r)
            tile[rl + r][cf*16 + (lane&15)] = acc[cf][r] * scale;
    __syncthreads();
    int h = ct >> 6;   // ct is a multiple of 64, exactly one head per tile
    if (MODE == 0) {
        int dh  = threadIdx.x & 63;
        int pr0 = threadIdx.x >> 6;
        #pragma unroll
        for (int it = 0; it < 16; ++it) {
            int pl = pr0 + it*4;
            int gr = tm + pl;
            int bb = gr / posPer, pos = gr - bb*posPer;
            out[((size_t)(bb*CH + h)*posPer + pos)*64 + dh] = f2bf(tile[pl][dh]);
        }
    } else {
        int ml = threadIdx.x & 63;
        int gr = tm + ml;
        int bb = gr / posPer, pos = gr - bb*posPer;
        int dh0 = threadIdx.x >> 6;
        #pragma unroll
        for (int it = 0; it < 16; ++it) {
            int dh = dh0 + it*4;
            out[((size_t)(bb*CH + h)*64 + dh)*posPer + pos] = f2bf(tile[ml][dh]);
        }
    }
}

// ---- scores: S = qp @ kp^T for one (b,h), 144 x 64 m-tile ----
// PHASE 0: per-(t,m) partial max / sumexp over the 24 rows of each t
// PHASE 1: a = exp(S-gmax)/gsum (masked->0), write attn_vis + per-tile rowsums
template<int PHASE>
__global__ __launch_bounds__(256) void scores_kernel(
    const unsigned short* __restrict__ qp, const unsigned short* __restrict__ kp,
    const int* __restrict__ mask,
    float* __restrict__ pmax, float* __restrict__ psum,
    const float* __restrict__ gmax, const float* __restrict__ gsum,
    float* __restrict__ avis, float* __restrict__ rowpart)
{
    __shared__ float S[CTN][65];
    int mt = blockIdx.x;
    int h = blockIdx.y, b = blockIdx.z;
    int lane = threadIdx.x & 63, wave = threadIdx.x >> 6;
    const unsigned short* qbase = qp + (size_t)(b*CH + h)*CTN*64;
    const unsigned short* kbase = kp + (size_t)(b*CH + h)*CTL*64;
    int koff = 8*(lane>>4);
    f32x4 acc[3][4] = {};
    for (int k0 = 0; k0 < 64; k0 += 32) {
        bf16x8 bfr[4];
        #pragma unroll
        for (int cf = 0; cf < 4; ++cf)
            bfr[cf] = ldbf8(kbase + (size_t)(mt*64 + cf*16 + (lane&15))*64 + k0 + koff);
        #pragma unroll
        for (int i = 0; i < 3; ++i) {
            int rt = wave + 4*i;
            if (rt < 9) {
                bf16x8 a = ldbf8(qbase + (size_t)(rt*16 + (lane&15))*64 + k0 + koff);
                #pragma unroll
                for (int cf = 0; cf < 4; ++cf)
                    acc[i][cf] = MFMA16(a, bfr[cf], acc[i][cf]);
            }
        }
    }
    #pragma unroll
    for (int i = 0; i < 3; ++i) {
        int rt = wave + 4*i;
        if (rt < 9) {
            #pragma unroll
            for (int cf = 0; cf < 4; ++cf)
                #pragma unroll
                for (int r = 0; r < 4; ++r)
                    S[rt*16 + 4*(lane>>4) + r][cf*16 + (lane&15)] = acc[i][cf][r];
        }
    }
    __syncthreads();
    int mg0 = mt*64;
    if (PHASE == 0) {
        for (int task = threadIdx.x; task < CT*64; task += 256) {
            int t = task >> 6, ml = task & 63;
            int mg = mg0 + ml;
            float mx = -INFINITY;
            float sv[24];
            #pragma unroll
            for (int i = 0; i < 24; ++i) {
                int tn = t*24 + i;
                bool msk = mask[(size_t)tn*CTL + mg] != 0;
                float s = msk ? -INFINITY : S[tn][ml];
                sv[i] = s;
                mx = fmaxf(mx, s);
            }
            float sum = 0.f;
            if (mx > -INFINITY) {
                #pragma unroll
                for (int i = 0; i < 24; ++i)
                    if (sv[i] > -INFINITY) sum += __expf(sv[i] - mx);
            }
            size_t idx = ((size_t)(b*CH + h)*CT + t)*CTL + mg;
            pmax[idx] = mx; psum[idx] = sum;
        }
    } else {
        for (int it = 0; it < 36; ++it) {
            int row = 4*it + wave;
            int mg = mg0 + lane;
            int t = row / 24;
            size_t gidx = ((size_t)b*CT + t)*CTL + mg;
            float g = gmax[gidx], gs = gsum[gidx];
            bool msk = mask[(size_t)row*CTL + mg] != 0;
            float a = (!msk && gs > 0.f) ? __expf(S[row][lane] - g) / gs : 0.f;
            avis[((size_t)(b*CH + h)*CTN + row)*CTL + mg] = a;
            float s = a;
            #pragma unroll
            for (int o = 1; o < 64; o <<= 1) s += __shfl_xor(s, o);
            if (lane == 0)
                rowpart[((size_t)(b*CH + h)*CTN + row)*CMT + mt] = s;
        }
    }
}

// ---- combine partial softmax stats across heads ----
__global__ void combine_kernel(const float* __restrict__ pmax, const float* __restrict__ psum,
                               float* __restrict__ gmax, float* __restrict__ gsum){
    size_t i = (size_t)blockIdx.x*blockDim.x + threadIdx.x;
    if (i >= (size_t)CB*CT*CTL) return;
    int m = (int)(i % CTL);
    size_t bt = i / CTL;
    int t = (int)(bt % CT), b = (int)(bt / CT);
    float pm[CH], ps[CH];
    float mx = -INFINITY;
    #pragma unroll
    for (int h = 0; h < CH; ++h) {
        size_t idx = ((size_t)(b*CH + h)*CT + t)*CTL + m;
        pm[h] = pmax[idx]; ps[h] = psum[idx];
        mx = fmaxf(mx, pm[h]);
    }
    float s = 0.f;
    if (mx > -INFINITY) {
        #pragma unroll
        for (int h = 0; h < CH; ++h)
            if (pm[h] > -INFINITY) s += ps[h]*__expf(pm[h] - mx);
    }
    gmax[i] = mx; gsum[i] = s;
}

// ---- reduce per-tile rowsums ----
__global__ void rowsum_kernel(const float* __restrict__ rowpart, float* __restrict__ rowsum){
    int i = blockIdx.x*blockDim.x + threadIdx.x;
    if (i >= CB*CH*CTN) return;
    float s = 0.f;
    for (int j = 0; j < CMT; ++j) s += rowpart[(size_t)i*CMT + j];
    rowsum[i] = s;
}

// ---- PV: out_h = (a @ vp) / (rowsum+EPS), write bf16 head-gathered ----
__global__ __launch_bounds__(64) void pv_kernel(
    const float* __restrict__ avis, const unsigned short* __restrict__ vpT,
    const float* __restrict__ rowsum, unsigned short* __restrict__ oh)
{
    int rt = blockIdx.x;
    int h = blockIdx.y, b = blockIdx.z;
    int lane = threadIdx.x;
    const float* abase = avis + ((size_t)(b*CH + h)*CTN + rt*16)*CTL;
    const unsigned short* vb = vpT + (size_t)(b*CH + h)*64*CTL;
    int koff = 8*(lane>>4);
    f32x4 acc[4] = {};
    for (int m0 = 0; m0 < CTL; m0 += 32) {
        bf16x8 a = cvt8(abase + (size_t)(lane&15)*CTL + m0 + koff);
        #pragma unroll
        for (int cf = 0; cf < 4; ++cf) {
            bf16x8 bv = ldbf8(vb + (size_t)(cf*16 + (lane&15))*CTL + m0 + koff);
            acc[cf] = MFMA16(a, bv, acc[cf]);
        }
    }
    int rbase = rt*16 + 4*(lane>>4);
    #pragma unroll
    for (int r = 0; r < 4; ++r) {
        int row = rbase + r;
        float inv = 1.f / (rowsum[(size_t)(b*CH + h)*CTN + row] + CEPS);
        #pragma unroll
        for (int cf = 0; cf < 4; ++cf) {
            int dh = cf*16 + (lane&15);
            oh[((size_t)b*CTN + row)*CD + h*64 + dh] = f2bf(acc[cf][r] * inv);
        }
    }
}

// ---- output projection: out = oh @ Wo^T (fp32 result) ----
__global__ __launch_bounds__(256) void outproj_kernel(
    const unsigned short* __restrict__ A, const unsigned short* __restrict__ W,
    float* __restrict__ out)
{
    int tm = blockIdx.x*64, ct = blockIdx.y*64;
    int lane = threadIdx.x & 63, wave = threadIdx.x >> 6;
    int arow = tm + wave*16 + (lane&15);
    int koff = 8*(lane>>4);
    f32x4 acc[4] = {};
    for (int k0 = 0; k0 < CD; k0 += 32) {
        bf16x8 a = ldbf8(A + (size_t)arow*CD + k0 + koff);
        #pragma unroll
        for (int cf = 0; cf < 4; ++cf) {
            bf16x8 b = ldbf8(W + (size_t)(ct + cf*16 + (lane&15))*CD + k0 + koff);
            acc[cf] = MFMA16(a, b, acc[cf]);
        }
    }
    int rbase = tm + wave*16 + 4*(lane>>4);
    #pragma unroll
    for (int r = 0; r < 4; ++r)
        #pragma unroll
        for (int cf = 0; cf < 4; ++cf)
            out[(size_t)(rbase + r)*CD + ct + cf*16 + (lane&15)] = acc[cf][r];
}

extern "C" void kernel_launch(void* const* d_in, const int* in_sizes, int n_in,
                              void* d_out, int out_size, void* d_ws, size_t ws_size,
                              hipStream_t stream)
{
    const float* q    = (const float*)d_in[0];
    const float* k    = (const float*)d_in[1];
    const float* v    = (const float*)d_in[2];
    const int*   mask = (const int*)  d_in[3];
    const float* Wq   = (const float*)d_in[4];
    const float* Wk   = (const float*)d_in[5];
    const float* Wv   = (const float*)d_in[6];
    const float* Wo   = (const float*)d_in[7];

    float* out0 = (float*)d_out;
    float* avis = out0 + (size_t)CB*CTN*CD;   // 589824 floats, then B*H*TN*TL

    char* p = (char*)d_ws;
    auto alloc = [&](size_t bytes) -> char* {
        char* r = p; p += (bytes + 255) & ~(size_t)255; return r;
    };
    unsigned short* Wq_bf = (unsigned short*)alloc((size_t)CD*CD*2);
    unsigned short* Wk_bf = (unsigned short*)alloc((size_t)CD*CD*2);
    unsigned short* Wv_bf = (unsigned short*)alloc((size_t)CD*CD*2);
    unsigned short* Wo_bf = (unsigned short*)alloc((size_t)CD*CD*2);
    unsigned short* qp    = (unsigned short*)alloc((size_t)CB*CH*CTN*64*2);
    unsigned short* kp    = (unsigned short*)alloc((size_t)CB*CH*CTL*64*2);
    unsigned short* vpT   = (unsigned short*)alloc((size_t)CB*CH*64*CTL*2);
    float* pmax    = (float*)alloc((size_t)CB*CH*CT*CTL*4);
    float* psum    = (float*)alloc((size_t)CB*CH*CT*CTL*4);
    float* gmax    = (float*)alloc((size_t)CB*CT*CTL*4);
    float* gsum    = (float*)alloc((size_t)CB*CT*CTL*4);
    float* rowpart = (float*)alloc((size_t)CB*CH*CTN*CMT*4);
    float* rowsum  = (float*)alloc((size_t)CB*CH*CTN*4);
    unsigned short* oh = (unsigned short*)alloc((size_t)CB*CTN*CD*2);

    // 1. weights -> bf16
    cvt_w_kernel<<<(4*CD*CD + 255)/256, 256, 0, stream>>>(Wq, Wk, Wv, Wo,
                                                          Wq_bf, Wk_bf, Wv_bf, Wo_bf);
    // 2. projections
    proj_kernel<0><<<dim3(CB*CTN/64, CD/64), 256, 0, stream>>>(q, Wq_bf, qp, CTN, 0.125f);
    proj_kernel<0><<<dim3(CB*CTL/64, CD/64), 256, 0, stream>>>(k, Wk_bf, kp, CTL, 1.0f);
    proj_kernel<1><<<dim3(CB*CTL/64, CD/64), 256, 0, stream>>>(v, Wv_bf, vpT, CTL, 1.0f);
    // 3. scores pass A: partial softmax stats
    scores_kernel<0><<<dim3(CMT, CH, CB), 256, 0, stream>>>(qp, kp, mask,
        pmax, psum, nullptr, nullptr, nullptr, nullptr);
    // 4. combine across heads
    combine_kernel<<<((CB*CT*CTL) + 255)/256, 256, 0, stream>>>(pmax, psum, gmax, gsum);
    // 5. scores pass B: attn_vis + rowsums
    scores_kernel<1><<<dim3(CMT, CH, CB), 256, 0, stream>>>(qp, kp, mask,
        nullptr, nullptr, gmax, gsum, avis, rowpart);
    // 6. rowsum reduce
    rowsum_kernel<<<((CB*CH*CTN) + 255)/256, 256, 0, stream>>>(rowpart, rowsum);
    // 7. PV
    pv_kernel<<<dim3(CTN/16, CH, CB), 64, 0, stream>>>(avis, vpT, rowsum, oh);
    // 8. output projection
    outproj_kernel<<<dim3(CB*CTN/64, CD/64), 256, 0, stream>>>(oh, Wo_bf, out0);
}